// Round 6
// baseline (569.436 us; speedup 1.0000x reference)
//
#include <hip/hip_runtime.h>
#include <cstdint>
#include <cstddef>

// GRU (reset_after) + dense(1)+sigmoid, masked by per-batch length t.
// R6 = R5 structure (2 waves x 64 lanes / sequence; wave w owns h-cols
// [32w,32w+32); lane k-half splits the reduction; ONE barrier/step;
// v_permlane32_swap_b32 VALU combine; x-row register prefetch; z/r weights
// pre-negated, c weights pre-doubled) with the R4-proven write discipline:
// ONLY half-0 lanes (lane<32 of each wave) write h' and p. Lower-lane
// combine results are correct under every permlane32_swap semantics variant;
// upper-half sums are never consumed.

typedef float v2f __attribute__((ext_vector_type(2)));
typedef float v4f __attribute__((ext_vector_type(4)));

__device__ __forceinline__ void pkfma(v2f& acc, const v2f a, const v2f b) {
    // acc += a * b (packed 2xfp32, single VOP3P instruction)
    asm("v_pk_fma_f32 %0, %1, %2, %0" : "+v"(acc) : "v"(a), "v"(b));
}

// Butterfly sum across the xor-32 lane boundary using v_permlane32_swap_b32.
// With a==b==v on input, lanes <32 receive v[i]+v[i^32] under all parallel
// variants (and even sequential ones); only lane<32 results are consumed.
__device__ __forceinline__ float xor32_sum(float v) {
    float a = v, b = v;
    asm("v_permlane32_swap_b32 %0, %1" : "+v"(a), "+v"(b));
    return a + b;
}

__device__ __forceinline__ float frcp(float x) { return __builtin_amdgcn_rcpf(x); }

#define NT 128

__global__ __launch_bounds__(NT, 1) void gru2_kernel(
    const float* __restrict__ xg,      // (512,1024,24)
    const int*   __restrict__ tg,      // (512,)
    const float* __restrict__ Wg,      // (24,192)
    const float* __restrict__ Ug,      // (64,192)
    const float* __restrict__ bg,      // (2,192)
    const float* __restrict__ Wdg,     // (64,1)
    const float* __restrict__ bdg,     // (1,)
    float*       __restrict__ outg)    // (512,1024)
{
    const int b    = blockIdx.x;
    const int tid  = threadIdx.x;
    const int wv   = tid >> 6;              // wave 0/1
    const int ln   = tid & 63;
    const int half = ln >> 5;               // k-half 0/1
    const int cj   = (wv << 5) + (ln & 31); // owned h column 0..63

    __shared__ __align__(16) float xbuf[1536];      // 64 steps x 24 floats
    __shared__ __align__(16) float h_lds[2][64];    // double-buffered state
    __shared__ __align__(16) float p_lds[64 * 66];  // [step][col], pad 66
    __shared__ float o_last;

    const int   t    = tg[b];
    float*      outb = outg + (size_t)b * 1024;
    const float bdv  = bdg[0];

    if (t <= 0) {
        const float fill = frcp(1.f + __expf(-bdv));
        for (int i = tid; i < 1024; i += NT) outb[i] = fill;
        return;
    }

    // ---- weight preload: lane's k-half of columns {cj, 64+cj, 128+cj} ----
    // z,r: NEGATED (sigmoid(v) = rcp(1+exp(-v)) -> accumulate -v directly)
    // c  : DOUBLED (tanh(u) = 1 - 2 rcp(1+exp(2u)) -> accumulate 2u directly)
    v2f Uz[16], Ur[16], Uc[16];
    #pragma unroll
    for (int k = 0; k < 16; ++k) {
        const float* r0 = Ug + (half * 32 + 2 * k)     * 192;
        const float* r1 = Ug + (half * 32 + 2 * k + 1) * 192;
        Uz[k] = (v2f){ -r0[cj],           -r1[cj]           };
        Ur[k] = (v2f){ -r0[64 + cj],      -r1[64 + cj]      };
        Uc[k] = (v2f){ 2.f * r0[128 + cj], 2.f * r1[128 + cj] };
    }
    v2f Wz[6], Wr[6], Wc[6];
    #pragma unroll
    for (int d = 0; d < 6; ++d) {
        const float* r0 = Wg + (half * 12 + 2 * d)     * 192;
        const float* r1 = Wg + (half * 12 + 2 * d + 1) * 192;
        Wz[d] = (v2f){ -r0[cj],           -r1[cj]           };
        Wr[d] = (v2f){ -r0[64 + cj],      -r1[64 + cj]      };
        Wc[d] = (v2f){ 2.f * r0[128 + cj], 2.f * r1[128 + cj] };
    }
    // biases (transformed to match), added AFTER the cross-half combine
    const float bzn  = -(bg[cj]      + bg[192 + cj]);
    const float brn  = -(bg[64 + cj] + bg[256 + cj]);
    const float b0c2 = 2.f * bg[128 + cj];
    const float b1c2 = 2.f * bg[320 + cj];
    const float wdj  = Wdg[cj];

    const float* xb = xg + (size_t)b * 24576;   // 1024*24

    // ---- stage chunk 0 (384 v4f / 128 threads = 3 each); zero h buf 0 ----
    {
        const v4f* src = (const v4f*)xb;
        v4f s0 = src[tid], s1 = src[tid + 128], s2 = src[tid + 256];
        v4f* dst = (v4f*)xbuf;
        dst[tid] = s0; dst[tid + 128] = s1; dst[tid + 256] = s2;
    }
    if (tid < 64) h_lds[0][tid] = 0.f;
    v4f pf0, pf1, pf2;
    if (t > 64) {
        const v4f* ns = (const v4f*)(xb + 1536);
        pf0 = ns[tid]; pf1 = ns[tid + 128]; pf2 = ns[tid + 256];
    }
    __syncthreads();

    float hold = 0.f;   // this lane's column state h_cj (redundant per half)

    for (int base = 0; base < t; base += 64) {
        const int cnt = (t - base < 64) ? (t - base) : 64;

        if (base > 0) {
            // previous chunk fully done (step barrier). Commit prefetched x,
            // reduce previous chunk's outputs, then prefetch next chunk.
            v4f* dst = (v4f*)xbuf;
            dst[tid] = pf0; dst[tid + 128] = pf1; dst[tid + 256] = pf2;
            if (tid < 64) {
                const v2f* pr = (const v2f*)(p_lds + tid * 66);
                v2f s2 = (v2f){0.f, 0.f};
                #pragma unroll
                for (int i = 0; i < 32; ++i) s2 += pr[i];
                outb[base - 64 + tid] = frcp(1.f + __expf(-(s2.x + s2.y + bdv)));
            }
            __syncthreads();   // xbuf commit + reduce reads complete
            if (base + 64 < t) {
                const v4f* ns = (const v4f*)(xb + (size_t)(base + 64) * 24);
                pf0 = ns[tid]; pf1 = ns[tid + 128]; pf2 = ns[tid + 256];
            }
        }

        // x row 0 of this chunk into registers
        v4f xv0, xv1, xv2;
        {
            const v4f* xr = (const v4f*)(xbuf + half * 12);
            xv0 = xr[0]; xv1 = xr[1]; xv2 = xr[2];
        }

        for (int c = 0; c < cnt; ++c) {
            const int rb = c & 1;          // h buffer written last step
            const v4f* hr = (const v4f*)(h_lds[rb] + (half << 5));

            // prefetch next step's x row (off-chain; row (c+1)&63 garbage-safe
            // on the last step, discarded at the chunk boundary)
            v4f nx0, nx1, nx2;
            {
                const v4f* xr = (const v4f*)(xbuf + ((c + 1) & 63) * 24 + half * 12);
                nx0 = xr[0]; nx1 = xr[1]; nx2 = xr[2];
            }

            v2f za = (v2f){0.f, 0.f}, ra = za, ca = za, xca = za;
            #pragma unroll
            for (int i = 0; i < 8; ++i) {
                const v4f h = hr[i];
                pkfma(za, Uz[2 * i], h.lo); pkfma(za, Uz[2 * i + 1], h.hi);
                pkfma(ra, Ur[2 * i], h.lo); pkfma(ra, Ur[2 * i + 1], h.hi);
                pkfma(ca, Uc[2 * i], h.lo); pkfma(ca, Uc[2 * i + 1], h.hi);
            }
            pkfma(za,  Wz[0], xv0.lo); pkfma(za,  Wz[1], xv0.hi);
            pkfma(ra,  Wr[0], xv0.lo); pkfma(ra,  Wr[1], xv0.hi);
            pkfma(xca, Wc[0], xv0.lo); pkfma(xca, Wc[1], xv0.hi);
            pkfma(za,  Wz[2], xv1.lo); pkfma(za,  Wz[3], xv1.hi);
            pkfma(ra,  Wr[2], xv1.lo); pkfma(ra,  Wr[3], xv1.hi);
            pkfma(xca, Wc[2], xv1.lo); pkfma(xca, Wc[3], xv1.hi);
            pkfma(za,  Wz[4], xv2.lo); pkfma(za,  Wz[5], xv2.hi);
            pkfma(ra,  Wr[4], xv2.lo); pkfma(ra,  Wr[5], xv2.hi);
            pkfma(xca, Wc[4], xv2.lo); pkfma(xca, Wc[5], xv2.hi);

            // horizontal + cross-half combine (pure VALU, no LDS);
            // only lane<32 results are consumed below.
            const float zsn  = xor32_sum(za.x + za.y);    // -(xz+hz) partial
            const float rsn  = xor32_sum(ra.x + ra.y);    // -(xr+hr) partial
            const float hcs2 = xor32_sum(ca.x + ca.y);    // 2*hc partial
            const float xcs2 = xor32_sum(xca.x + xca.y);  // 2*xc partial

            const float z  = frcp(1.f + __expf(zsn + bzn));
            const float r  = frcp(1.f + __expf(rsn + brn));
            const float y  = fmaf(r, hcs2 + b1c2, xcs2 + b0c2);  // 2*(xc + r*hc)
            const float cg = 1.f - 2.f * frcp(1.f + __expf(y));
            const float hn = fmaf(z, hold - cg, cg);             // z*h + (1-z)*c
            hold = hn;

            if (half == 0) {                    // single (verified-correct) writer
                h_lds[rb ^ 1][cj]  = hn;        // next step's state buffer
                p_lds[c * 66 + cj] = hn * wdj;  // output partial
            }
            __syncthreads();   // ONE barrier per step

            xv0 = nx0; xv1 = nx1; xv2 = nx2;
        }
    }

    // ---- final (possibly partial) chunk reduce ----
    const int lastbase = ((t - 1) >> 6) << 6;
    const int lastcnt  = t - lastbase;
    if (tid < lastcnt) {
        const v2f* pr = (const v2f*)(p_lds + tid * 66);
        v2f s2 = (v2f){0.f, 0.f};
        #pragma unroll
        for (int i = 0; i < 32; ++i) s2 += pr[i];
        const float o = frcp(1.f + __expf(-(s2.x + s2.y + bdv)));
        outb[lastbase + tid] = o;
        if (tid == lastcnt - 1) o_last = o;
    }
    __syncthreads();
    // ---- constant tail fill (h frozen for s >= t) ----
    const float fill = o_last;
    for (int i = t + tid; i < 1024; i += NT) outb[i] = fill;
}

extern "C" void kernel_launch(void* const* d_in, const int* in_sizes, int n_in,
                              void* d_out, int out_size, void* d_ws, size_t ws_size,
                              hipStream_t stream) {
    (void)in_sizes; (void)n_in; (void)d_ws; (void)ws_size; (void)out_size;
    const float* x  = (const float*)d_in[0];
    const int*   t  = (const int*)d_in[1];
    const float* W  = (const float*)d_in[2];
    const float* U  = (const float*)d_in[3];
    const float* bb = (const float*)d_in[4];
    const float* Wd = (const float*)d_in[5];
    const float* bd = (const float*)d_in[6];
    float* out = (float*)d_out;

    hipLaunchKernelGGL(gru2_kernel, dim3(512), dim3(NT), 0, stream,
                       x, t, W, U, bb, Wd, bd, out);
}

// Round 9
// 562.715 us; speedup vs baseline: 1.0119x; 1.0119x over previous
//
#include <hip/hip_runtime.h>
#include <cstdint>
#include <cstddef>

// GRU (reset_after) + dense(1)+sigmoid, masked by per-batch length t.
// R9 = R6 (proven-pass: 2 waves x 64 lanes / sequence; wave w owns h-cols
// [32w,32w+32); lane k-half splits the reduction; ONE barrier/step;
// permlane32_swap combine; __expf/rcpf builtins; NO register pinning)
// with the x-part matvec moved OFF the critical path:
//  - step s's x-contributions are computed in step s-1's SHADOW region
//    (after h' write, before the barrier) from the prefetched x row
//  - biases folded into half-0 shadow/accumulator inits (no chain adds)
//  - r-gate chain issued first (exp latency overlaps z/c chains)
//  - post-barrier chain: 8 ds_read_b128 -> 48 pkfma -> 3 permlanes -> gates

typedef float v2f __attribute__((ext_vector_type(2)));
typedef float v4f __attribute__((ext_vector_type(4)));

__device__ __forceinline__ void pkfma(v2f& acc, const v2f a, const v2f b) {
    // acc += a * b (packed 2xfp32, single VOP3P instruction)
    asm("v_pk_fma_f32 %0, %1, %2, %0" : "+v"(acc) : "v"(a), "v"(b));
}

// Butterfly sum across the xor-32 lane boundary via v_permlane32_swap_b32.
// Proven correct in R4/R6 usage (both halves receive lo+hi).
__device__ __forceinline__ float xor32_sum(float v) {
    float a = v, b = v;
    asm("v_permlane32_swap_b32 %0, %1" : "+v"(a), "+v"(b));
    return a + b;
}

__device__ __forceinline__ float frcp(float x) { return __builtin_amdgcn_rcpf(x); }

#define NT 128

// Shadow x-part: per-lane k-half partials for the NEXT step's gates,
// biases folded into half-0 inits. Writes xz_sh, xr_sh (k-half partials)
// and xct_sh (fully combined 2*xc + 2*b0c).
#define SHADOW(XA, XB, XC)                                                   \
    {                                                                        \
        v2f sz = (v2f){bzn_h, 0.f};                                          \
        v2f sr = (v2f){brn_h, 0.f};                                          \
        v2f sc = (v2f){b0c2_h, 0.f};                                         \
        pkfma(sz, Wz[0], (XA).lo); pkfma(sz, Wz[1], (XA).hi);                \
        pkfma(sr, Wr[0], (XA).lo); pkfma(sr, Wr[1], (XA).hi);                \
        pkfma(sc, Wc[0], (XA).lo); pkfma(sc, Wc[1], (XA).hi);                \
        pkfma(sz, Wz[2], (XB).lo); pkfma(sz, Wz[3], (XB).hi);                \
        pkfma(sr, Wr[2], (XB).lo); pkfma(sr, Wr[3], (XB).hi);                \
        pkfma(sc, Wc[2], (XB).lo); pkfma(sc, Wc[3], (XB).hi);                \
        pkfma(sz, Wz[4], (XC).lo); pkfma(sz, Wz[5], (XC).hi);                \
        pkfma(sr, Wr[4], (XC).lo); pkfma(sr, Wr[5], (XC).hi);                \
        pkfma(sc, Wc[4], (XC).lo); pkfma(sc, Wc[5], (XC).hi);                \
        xz_sh  = sz.x + sz.y;                                                \
        xr_sh  = sr.x + sr.y;                                                \
        xct_sh = xor32_sum(sc.x + sc.y);                                     \
    }

__global__ __launch_bounds__(NT, 1) void gru2_kernel(
    const float* __restrict__ xg,      // (512,1024,24)
    const int*   __restrict__ tg,      // (512,)
    const float* __restrict__ Wg,      // (24,192)
    const float* __restrict__ Ug,      // (64,192)
    const float* __restrict__ bg,      // (2,192)
    const float* __restrict__ Wdg,     // (64,1)
    const float* __restrict__ bdg,     // (1,)
    float*       __restrict__ outg)    // (512,1024)
{
    const int b    = blockIdx.x;
    const int tid  = threadIdx.x;
    const int wv   = tid >> 6;              // wave 0/1
    const int ln   = tid & 63;
    const int half = ln >> 5;               // k-half 0/1
    const int cj   = (wv << 5) + (ln & 31); // owned h column 0..63

    __shared__ __align__(16) float xbuf[1536];      // 64 steps x 24 floats
    __shared__ __align__(16) float h_lds[2][64];    // double-buffered state
    __shared__ __align__(16) float p_lds[64 * 66];  // [step][col], pad 66
    __shared__ float o_last;

    const int   t    = tg[b];
    float*      outb = outg + (size_t)b * 1024;
    const float bdv  = bdg[0];

    if (t <= 0) {
        const float fill = frcp(1.f + __expf(-bdv));
        for (int i = tid; i < 1024; i += NT) outb[i] = fill;
        return;
    }

    // ---- weight preload: lane's k-half of columns {cj, 64+cj, 128+cj} ----
    // z,r: NEGATED (sigmoid(v) = rcp(1+exp(-v)));  c: DOUBLED (tanh identity)
    v2f Uz[16], Ur[16], Uc[16];
    #pragma unroll
    for (int k = 0; k < 16; ++k) {
        const float* r0 = Ug + (half * 32 + 2 * k)     * 192;
        const float* r1 = Ug + (half * 32 + 2 * k + 1) * 192;
        Uz[k] = (v2f){ -r0[cj],           -r1[cj]           };
        Ur[k] = (v2f){ -r0[64 + cj],      -r1[64 + cj]      };
        Uc[k] = (v2f){ 2.f * r0[128 + cj], 2.f * r1[128 + cj] };
    }
    v2f Wz[6], Wr[6], Wc[6];
    #pragma unroll
    for (int d = 0; d < 6; ++d) {
        const float* r0 = Wg + (half * 12 + 2 * d)     * 192;
        const float* r1 = Wg + (half * 12 + 2 * d + 1) * 192;
        Wz[d] = (v2f){ -r0[cj],           -r1[cj]           };
        Wr[d] = (v2f){ -r0[64 + cj],      -r1[64 + cj]      };
        Wc[d] = (v2f){ 2.f * r0[128 + cj], 2.f * r1[128 + cj] };
    }
    // biases folded into HALF-0 inits only (permlane sum counts them once)
    const float bzn_h  = (half == 0) ? -(bg[cj]      + bg[192 + cj]) : 0.f;
    const float brn_h  = (half == 0) ? -(bg[64 + cj] + bg[256 + cj]) : 0.f;
    const float b0c2_h = (half == 0) ? 2.f * bg[128 + cj] : 0.f;
    const float b1c2_h = (half == 0) ? 2.f * bg[320 + cj] : 0.f;
    const float wdj    = Wdg[cj];

    const float* xb = xg + (size_t)b * 24576;   // 1024*24

    // ---- stage chunk 0 (384 v4f / 128 threads = 3 each); zero h buf 0 ----
    {
        const v4f* src = (const v4f*)xb;
        v4f s0 = src[tid], s1 = src[tid + 128], s2 = src[tid + 256];
        v4f* dst = (v4f*)xbuf;
        dst[tid] = s0; dst[tid + 128] = s1; dst[tid + 256] = s2;
    }
    if (tid < 64) h_lds[0][tid] = 0.f;
    v4f pf0, pf1, pf2;
    if (t > 64) {
        const v4f* ns = (const v4f*)(xb + 1536);
        pf0 = ns[tid]; pf1 = ns[tid + 128]; pf2 = ns[tid + 256];
    }
    __syncthreads();

    float hold = 0.f;                 // lane's column state h_cj
    float xz_sh, xr_sh, xct_sh;       // shadow x-part for the upcoming step
    {
        // prologue shadow: step 0's x-part from xbuf row 0
        const v4f* xr0 = (const v4f*)(xbuf + half * 12);
        v4f a0 = xr0[0], a1 = xr0[1], a2 = xr0[2];
        SHADOW(a0, a1, a2);
    }

    for (int base = 0; base < t; base += 64) {
        const int cnt = (t - base < 64) ? (t - base) : 64;

        if (base > 0) {
            // previous chunk fully done (step barrier). Commit prefetched x,
            // reduce previous chunk's outputs, re-shadow step base's x-part.
            v4f* dst = (v4f*)xbuf;
            dst[tid] = pf0; dst[tid + 128] = pf1; dst[tid + 256] = pf2;
            if (tid < 64) {
                const v2f* pr = (const v2f*)(p_lds + tid * 66);
                v2f s2 = (v2f){0.f, 0.f};
                #pragma unroll
                for (int i = 0; i < 32; ++i) s2 += pr[i];
                outb[base - 64 + tid] = frcp(1.f + __expf(-(s2.x + s2.y + bdv)));
            }
            __syncthreads();   // xbuf commit + reduce reads complete
            if (base + 64 < t) {
                const v4f* ns = (const v4f*)(xb + (size_t)(base + 64) * 24);
                pf0 = ns[tid]; pf1 = ns[tid + 128]; pf2 = ns[tid + 256];
            }
            // shadow for this chunk's step 0 (in-step shadow at c=63 used the
            // stale row 0; recompute from the freshly committed row 0)
            const v4f* xr0 = (const v4f*)(xbuf + half * 12);
            v4f a0 = xr0[0], a1 = xr0[1], a2 = xr0[2];
            SHADOW(a0, a1, a2);
        }

        for (int c = 0; c < cnt; ++c) {
            const int rb = c & 1;          // h buffer written last step

            // ---- chain head: h reads first in the DS queue ----
            const v4f* hr = (const v4f*)(h_lds[rb] + (half << 5));
            v4f hv[8];
            #pragma unroll
            for (int i = 0; i < 8; ++i) hv[i] = hr[i];

            // next x row for the upcoming shadow (arrives during FMA phase)
            v4f nx0, nx1, nx2;
            {
                const v4f* xrn = (const v4f*)(xbuf + ((c + 1) & 63) * 24 + half * 12);
                nx0 = xrn[0]; nx1 = xrn[1]; nx2 = xrn[2];
            }

            // ---- U-part chains, r FIRST (exp overlaps z/c chains) ----
            v2f ra = (v2f){xr_sh, 0.f};
            #pragma unroll
            for (int i = 0; i < 8; ++i) {
                pkfma(ra, Ur[2 * i], hv[i].lo); pkfma(ra, Ur[2 * i + 1], hv[i].hi);
            }
            const float rsn = xor32_sum(ra.x + ra.y);
            const float er  = __expf(rsn);           // cooks under z/c below

            v2f za = (v2f){xz_sh, 0.f};
            v2f ca = (v2f){b1c2_h, 0.f};
            #pragma unroll
            for (int i = 0; i < 8; ++i) {
                pkfma(za, Uz[2 * i], hv[i].lo); pkfma(za, Uz[2 * i + 1], hv[i].hi);
                pkfma(ca, Uc[2 * i], hv[i].lo); pkfma(ca, Uc[2 * i + 1], hv[i].hi);
            }
            const float zsn = xor32_sum(za.x + za.y);
            const float hcs = xor32_sum(ca.x + ca.y);   // 2*hc + 2*b1c

            const float z   = frcp(1.f + __expf(zsn));
            const float r   = frcp(1.f + er);
            const float zh  = z * hold;                 // off-chain
            const float omz = 1.f - z;                  // off-chain
            const float y   = fmaf(r, hcs, xct_sh);     // 2*(xc+b0c + r*(hc+b1c))
            const float cg  = 1.f - 2.f * frcp(1.f + __expf(y));
            const float hn  = fmaf(omz, cg, zh);        // z*h + (1-z)*c
            hold = hn;

            if (half == 0) {                    // single writer per column
                h_lds[rb ^ 1][cj]  = hn;        // next step's state buffer
                p_lds[c * 66 + cj] = hn * wdj;  // output partial
            }

            // ---- SHADOW: next step's x-part (off the h-chain) ----
            SHADOW(nx0, nx1, nx2);

            __syncthreads();   // ONE barrier per step
        }
    }

    // ---- final (possibly partial) chunk reduce ----
    const int lastbase = ((t - 1) >> 6) << 6;
    const int lastcnt  = t - lastbase;
    if (tid < lastcnt) {
        const v2f* pr = (const v2f*)(p_lds + tid * 66);
        v2f s2 = (v2f){0.f, 0.f};
        #pragma unroll
        for (int i = 0; i < 32; ++i) s2 += pr[i];
        const float o = frcp(1.f + __expf(-(s2.x + s2.y + bdv)));
        outb[lastbase + tid] = o;
        if (tid == lastcnt - 1) o_last = o;
    }
    __syncthreads();
    // ---- constant tail fill (h frozen for s >= t) ----
    const float fill = o_last;
    for (int i = t + tid; i < 1024; i += NT) outb[i] = fill;
}

extern "C" void kernel_launch(void* const* d_in, const int* in_sizes, int n_in,
                              void* d_out, int out_size, void* d_ws, size_t ws_size,
                              hipStream_t stream) {
    (void)in_sizes; (void)n_in; (void)d_ws; (void)ws_size; (void)out_size;
    const float* x  = (const float*)d_in[0];
    const int*   t  = (const int*)d_in[1];
    const float* W  = (const float*)d_in[2];
    const float* U  = (const float*)d_in[3];
    const float* bb = (const float*)d_in[4];
    const float* Wd = (const float*)d_in[5];
    const float* bd = (const float*)d_in[6];
    float* out = (float*)d_out;

    hipLaunchKernelGGL(gru2_kernel, dim3(512), dim3(NT), 0, stream,
                       x, t, W, U, bb, Wd, bd, out);
}

// Round 11
// 379.076 us; speedup vs baseline: 1.5022x; 1.4844x over previous
//
#include <hip/hip_runtime.h>
#include <cstdint>
#include <cstddef>

// GRU (reset_after) + dense(1)+sigmoid, masked by per-batch length t.
// R11 = R10 with the shufflevector indices made literal (compile fix).
// ONE WAVE per sequence (512 blocks x 64 threads), ZERO barriers.
// Lane j owns gate columns {j, 64+j, 128+j} with FULL K (no cross-lane
// combine). Weights as packed f16 pairs in VGPRs, consumed by
// v_dot2_f32_f16 (f32 accumulate): weight set 132 VGPRs, total ~220 -> fits.
// h state f16 in LDS: ds_write_b16 by owner lane, re-read same wave next
// step (in-order LDS pipe, no __syncthreads).
// z/r weights pre-negated, c weights pre-doubled (R6-proven folds).

typedef float  v2f __attribute__((ext_vector_type(2)));
typedef float  v4f __attribute__((ext_vector_type(4)));
typedef _Float16 h2 __attribute__((ext_vector_type(2)));
typedef _Float16 h8 __attribute__((ext_vector_type(8)));

__device__ __forceinline__ float frcp(float x) { return __builtin_amdgcn_rcpf(x); }

#if defined(__has_builtin)
#if __has_builtin(__builtin_amdgcn_fdot2)
#define HAVE_FDOT2 1
#endif
#endif

__device__ __forceinline__ float fdot2(h2 a, h2 b, float acc) {
#ifdef HAVE_FDOT2
    return __builtin_amdgcn_fdot2(a, b, acc, false);
#else
    return fmaf((float)a.x, (float)b.x, fmaf((float)a.y, (float)b.y, acc));
#endif
}

#define PAIR(v8, m) __builtin_shufflevector((v8), (v8), 2*(m), 2*(m)+1)

// 4 dot2s against one h8 vector, all pair indices literal
#define DOT4(acc, Warr, off, v)                              \
    acc = fdot2((Warr)[(off) + 0], PAIR((v), 0), acc);       \
    acc = fdot2((Warr)[(off) + 1], PAIR((v), 1), acc);       \
    acc = fdot2((Warr)[(off) + 2], PAIR((v), 2), acc);       \
    acc = fdot2((Warr)[(off) + 3], PAIR((v), 3), acc);

__global__ __launch_bounds__(64, 1) void gru1_kernel(
    const float* __restrict__ xg,      // (512,1024,24)
    const int*   __restrict__ tg,      // (512,)
    const float* __restrict__ Wg,      // (24,192)
    const float* __restrict__ Ug,      // (64,192)
    const float* __restrict__ bg,      // (2,192)
    const float* __restrict__ Wdg,     // (64,1)
    const float* __restrict__ bdg,     // (1,)
    float*       __restrict__ outg)    // (512,1024)
{
    const int b = blockIdx.x;
    const int j = threadIdx.x;          // lane 0..63

    __shared__ __align__(16) _Float16 h16[64];          // f16 state, 128 B
    __shared__ __align__(16) _Float16 xbuf[64 * 24];    // chunk of x, f16
    __shared__ __align__(16) float    p_lds[64 * 66];   // [step][lane], pad 66
    __shared__ float o_last;

    const int   t    = tg[b];
    float*      outb = outg + (size_t)b * 1024;
    const float bdv  = bdg[0];

    if (t <= 0) {
        const float fill = frcp(1.f + __expf(-bdv));
        for (int i = j; i < 1024; i += 64) outb[i] = fill;
        return;
    }

    // ---- weight preload: f16 pairs along K; z/r negated, c doubled ----
    h2 Uz[32], Ur[32], Uc[32];
    #pragma unroll
    for (int k = 0; k < 32; ++k) {
        const float* r0 = Ug + (2 * k)     * 192;
        const float* r1 = Ug + (2 * k + 1) * 192;
        Uz[k] = (h2){ (_Float16)(-r0[j]),            (_Float16)(-r1[j]) };
        Ur[k] = (h2){ (_Float16)(-r0[64 + j]),       (_Float16)(-r1[64 + j]) };
        Uc[k] = (h2){ (_Float16)(2.f * r0[128 + j]), (_Float16)(2.f * r1[128 + j]) };
    }
    h2 Wz[12], Wr[12], Wc[12];
    #pragma unroll
    for (int d = 0; d < 12; ++d) {
        const float* r0 = Wg + (2 * d)     * 192;
        const float* r1 = Wg + (2 * d + 1) * 192;
        Wz[d] = (h2){ (_Float16)(-r0[j]),            (_Float16)(-r1[j]) };
        Wr[d] = (h2){ (_Float16)(-r0[64 + j]),       (_Float16)(-r1[64 + j]) };
        Wc[d] = (h2){ (_Float16)(2.f * r0[128 + j]), (_Float16)(2.f * r1[128 + j]) };
    }
    const float bzn  = -(bg[j]      + bg[192 + j]);     // z: negated
    const float brn  = -(bg[64 + j] + bg[256 + j]);     // r: negated
    const float b0c2 = 2.f * bg[128 + j];               // c: doubled
    const float b1c2 = 2.f * bg[320 + j];
    const float wdj  = Wdg[j];

    const float* xb = xg + (size_t)b * 24576;   // 1024*24

    // ---- stage chunk 0: lane j handles x row j (24 f32 -> 24 f16) ----
    {
        const v4f* src = (const v4f*)(xb + j * 24);
        v4f g0 = src[0], g1 = src[1], g2 = src[2], g3 = src[3], g4 = src[4], g5 = src[5];
        h8 o0, o1, o2;
        #pragma unroll
        for (int i = 0; i < 4; ++i) {
            o0[i]     = (_Float16)g0[i];  o0[4 + i] = (_Float16)g1[i];
            o1[i]     = (_Float16)g2[i];  o1[4 + i] = (_Float16)g3[i];
            o2[i]     = (_Float16)g4[i];  o2[4 + i] = (_Float16)g5[i];
        }
        h8* dst = (h8*)(xbuf + j * 24);
        dst[0] = o0; dst[1] = o1; dst[2] = o2;
    }
    h16[j] = (_Float16)0.f;

    // prefetch chunk 1 (f32, converted at commit)
    v4f pf[6];
    if (t > 64) {
        const v4f* ns = (const v4f*)(xb + 1536 + j * 24);
        #pragma unroll
        for (int i = 0; i < 6; ++i) pf[i] = ns[i];
    }

    float hold = 0.f;   // lane j's own h_j (f32, full precision)

    for (int base = 0; base < t; base += 64) {
        const int cnt = (t - base < 64) ? (t - base) : 64;

        if (base > 0) {
            // previous chunk done. Reduce its outputs (before p_lds reuse),
            // commit prefetched x, prefetch next. Same-wave ordering only.
            {
                const v2f* pr = (const v2f*)(p_lds + j * 66);
                v2f s2 = (v2f){0.f, 0.f};
                #pragma unroll
                for (int i = 0; i < 32; ++i) s2 += pr[i];
                outb[base - 64 + j] = frcp(1.f + __expf(-(s2.x + s2.y + bdv)));
            }
            {
                h8 o0, o1, o2;
                #pragma unroll
                for (int i = 0; i < 4; ++i) {
                    o0[i]     = (_Float16)pf[0][i];  o0[4 + i] = (_Float16)pf[1][i];
                    o1[i]     = (_Float16)pf[2][i];  o1[4 + i] = (_Float16)pf[3][i];
                    o2[i]     = (_Float16)pf[4][i];  o2[4 + i] = (_Float16)pf[5][i];
                }
                h8* dst = (h8*)(xbuf + j * 24);
                dst[0] = o0; dst[1] = o1; dst[2] = o2;
            }
            if (base + 64 < t) {
                const v4f* ns = (const v4f*)(xb + (size_t)(base + 64) * 24 + j * 24);
                #pragma unroll
                for (int i = 0; i < 6; ++i) pf[i] = ns[i];
            }
        }

        for (int c = 0; c < cnt; ++c) {
            // ---- chain head: read full h (8 x 16B) and x row c (3 x 16B) ----
            const h8* hp = (const h8*)h16;
            h8 hv[8];
            #pragma unroll
            for (int i = 0; i < 8; ++i) hv[i] = hp[i];
            const h8* xp = (const h8*)(xbuf + c * 24);
            h8 xa = xp[0], xcv = xp[1], xe = xp[2];

            // ---- r-gate first: its exp cooks under the z/c dot streams ----
            float ran = brn;
            #pragma unroll
            for (int i = 0; i < 8; ++i) { DOT4(ran, Ur, 4 * i, hv[i]); }
            DOT4(ran, Wr, 0, xa); DOT4(ran, Wr, 4, xcv); DOT4(ran, Wr, 8, xe);
            const float er = __expf(ran);        // latency hidden under z/c dots

            float zan = bzn;
            #pragma unroll
            for (int i = 0; i < 8; ++i) { DOT4(zan, Uz, 4 * i, hv[i]); }
            DOT4(zan, Wz, 0, xa); DOT4(zan, Wz, 4, xcv); DOT4(zan, Wz, 8, xe);
            const float ez = __expf(zan);        // cooks under c dots

            float ca = b1c2, xca = b0c2;         // 2*(hc+b1c), 2*(xc+b0c)
            #pragma unroll
            for (int i = 0; i < 8; ++i) { DOT4(ca, Uc, 4 * i, hv[i]); }
            DOT4(xca, Wc, 0, xa); DOT4(xca, Wc, 4, xcv); DOT4(xca, Wc, 8, xe);

            const float r  = frcp(1.f + er);
            const float z  = frcp(1.f + ez);
            const float y  = fmaf(r, ca, xca);                 // 2*(xc + r*hc)
            const float cg = 1.f - 2.f * frcp(1.f + __expf(y));
            const float hn = fmaf(z, hold - cg, cg);           // z*h + (1-z)*c
            hold = hn;

            h16[j] = (_Float16)hn;          // next step's state (ds_write_b16)
            p_lds[c * 66 + j] = hn * wdj;   // output partial
        }
    }

    // ---- final (possibly partial) chunk reduce ----
    const int lastbase = ((t - 1) >> 6) << 6;
    const int lastcnt  = t - lastbase;
    if (j < lastcnt) {
        const v2f* pr = (const v2f*)(p_lds + j * 66);
        v2f s2 = (v2f){0.f, 0.f};
        #pragma unroll
        for (int i = 0; i < 32; ++i) s2 += pr[i];
        const float o = frcp(1.f + __expf(-(s2.x + s2.y + bdv)));
        outb[lastbase + j] = o;
        if (j == lastcnt - 1) o_last = o;
    }
    // ---- constant tail fill (same-wave visibility; R3-proven pattern) ----
    const float fill = o_last;
    for (int i = t + j; i < 1024; i += 64) outb[i] = fill;
}

extern "C" void kernel_launch(void* const* d_in, const int* in_sizes, int n_in,
                              void* d_out, int out_size, void* d_ws, size_t ws_size,
                              hipStream_t stream) {
    (void)in_sizes; (void)n_in; (void)d_ws; (void)ws_size; (void)out_size;
    const float* x  = (const float*)d_in[0];
    const int*   t  = (const int*)d_in[1];
    const float* W  = (const float*)d_in[2];
    const float* U  = (const float*)d_in[3];
    const float* bb = (const float*)d_in[4];
    const float* Wd = (const float*)d_in[5];
    const float* bd = (const float*)d_in[6];
    float* out = (float*)d_out;

    hipLaunchKernelGGL(gru1_kernel, dim3(512), dim3(64), 0, stream,
                       x, t, W, U, bb, Wd, bd, out);
}

// Round 12
// 377.667 us; speedup vs baseline: 1.5078x; 1.0037x over previous
//
#include <hip/hip_runtime.h>
#include <cstdint>
#include <cstddef>

// GRU (reset_after) + dense(1)+sigmoid, masked by per-batch length t.
// R12 = R11 with ONE change: each gate's dot chain runs x-part (W-dots)
// FIRST, then the h-part (U-dots). The 36 W-dots are independent of the
// h LDS read, so they issue during the ~120cy read-latency window that
// R11 left fully exposed (first U-dot of every chain needed hv).
// Structure unchanged: ONE WAVE per sequence (512 x 64), ZERO barriers,
// lane j owns gate columns {j,64+j,128+j} full-K, f16-pair weights in
// VGPRs via v_dot2_f32_f16, h state f16 in LDS (same-wave write->read),
// z/r weights pre-negated, c weights pre-doubled.

typedef float  v2f __attribute__((ext_vector_type(2)));
typedef float  v4f __attribute__((ext_vector_type(4)));
typedef _Float16 h2 __attribute__((ext_vector_type(2)));
typedef _Float16 h8 __attribute__((ext_vector_type(8)));

__device__ __forceinline__ float frcp(float x) { return __builtin_amdgcn_rcpf(x); }

#if defined(__has_builtin)
#if __has_builtin(__builtin_amdgcn_fdot2)
#define HAVE_FDOT2 1
#endif
#endif

__device__ __forceinline__ float fdot2(h2 a, h2 b, float acc) {
#ifdef HAVE_FDOT2
    return __builtin_amdgcn_fdot2(a, b, acc, false);
#else
    return fmaf((float)a.x, (float)b.x, fmaf((float)a.y, (float)b.y, acc));
#endif
}

#define PAIR(v8, m) __builtin_shufflevector((v8), (v8), 2*(m), 2*(m)+1)

// 4 dot2s against one h8 vector, all pair indices literal
#define DOT4(acc, Warr, off, v)                              \
    acc = fdot2((Warr)[(off) + 0], PAIR((v), 0), acc);       \
    acc = fdot2((Warr)[(off) + 1], PAIR((v), 1), acc);       \
    acc = fdot2((Warr)[(off) + 2], PAIR((v), 2), acc);       \
    acc = fdot2((Warr)[(off) + 3], PAIR((v), 3), acc);

__global__ __launch_bounds__(64, 1) void gru1_kernel(
    const float* __restrict__ xg,      // (512,1024,24)
    const int*   __restrict__ tg,      // (512,)
    const float* __restrict__ Wg,      // (24,192)
    const float* __restrict__ Ug,      // (64,192)
    const float* __restrict__ bg,      // (2,192)
    const float* __restrict__ Wdg,     // (64,1)
    const float* __restrict__ bdg,     // (1,)
    float*       __restrict__ outg)    // (512,1024)
{
    const int b = blockIdx.x;
    const int j = threadIdx.x;          // lane 0..63

    __shared__ __align__(16) _Float16 h16[64];          // f16 state, 128 B
    __shared__ __align__(16) _Float16 xbuf[64 * 24];    // chunk of x, f16
    __shared__ __align__(16) float    p_lds[64 * 66];   // [step][lane], pad 66
    __shared__ float o_last;

    const int   t    = tg[b];
    float*      outb = outg + (size_t)b * 1024;
    const float bdv  = bdg[0];

    if (t <= 0) {
        const float fill = frcp(1.f + __expf(-bdv));
        for (int i = j; i < 1024; i += 64) outb[i] = fill;
        return;
    }

    // ---- weight preload: f16 pairs along K; z/r negated, c doubled ----
    h2 Uz[32], Ur[32], Uc[32];
    #pragma unroll
    for (int k = 0; k < 32; ++k) {
        const float* r0 = Ug + (2 * k)     * 192;
        const float* r1 = Ug + (2 * k + 1) * 192;
        Uz[k] = (h2){ (_Float16)(-r0[j]),            (_Float16)(-r1[j]) };
        Ur[k] = (h2){ (_Float16)(-r0[64 + j]),       (_Float16)(-r1[64 + j]) };
        Uc[k] = (h2){ (_Float16)(2.f * r0[128 + j]), (_Float16)(2.f * r1[128 + j]) };
    }
    h2 Wz[12], Wr[12], Wc[12];
    #pragma unroll
    for (int d = 0; d < 12; ++d) {
        const float* r0 = Wg + (2 * d)     * 192;
        const float* r1 = Wg + (2 * d + 1) * 192;
        Wz[d] = (h2){ (_Float16)(-r0[j]),            (_Float16)(-r1[j]) };
        Wr[d] = (h2){ (_Float16)(-r0[64 + j]),       (_Float16)(-r1[64 + j]) };
        Wc[d] = (h2){ (_Float16)(2.f * r0[128 + j]), (_Float16)(2.f * r1[128 + j]) };
    }
    const float bzn  = -(bg[j]      + bg[192 + j]);     // z: negated
    const float brn  = -(bg[64 + j] + bg[256 + j]);     // r: negated
    const float b0c2 = 2.f * bg[128 + j];               // c: doubled
    const float b1c2 = 2.f * bg[320 + j];
    const float wdj  = Wdg[j];

    const float* xb = xg + (size_t)b * 24576;   // 1024*24

    // ---- stage chunk 0: lane j handles x row j (24 f32 -> 24 f16) ----
    {
        const v4f* src = (const v4f*)(xb + j * 24);
        v4f g0 = src[0], g1 = src[1], g2 = src[2], g3 = src[3], g4 = src[4], g5 = src[5];
        h8 o0, o1, o2;
        #pragma unroll
        for (int i = 0; i < 4; ++i) {
            o0[i]     = (_Float16)g0[i];  o0[4 + i] = (_Float16)g1[i];
            o1[i]     = (_Float16)g2[i];  o1[4 + i] = (_Float16)g3[i];
            o2[i]     = (_Float16)g4[i];  o2[4 + i] = (_Float16)g5[i];
        }
        h8* dst = (h8*)(xbuf + j * 24);
        dst[0] = o0; dst[1] = o1; dst[2] = o2;
    }
    h16[j] = (_Float16)0.f;

    // prefetch chunk 1 (f32, converted at commit)
    v4f pf[6];
    if (t > 64) {
        const v4f* ns = (const v4f*)(xb + 1536 + j * 24);
        #pragma unroll
        for (int i = 0; i < 6; ++i) pf[i] = ns[i];
    }

    float hold = 0.f;   // lane j's own h_j (f32, full precision)

    for (int base = 0; base < t; base += 64) {
        const int cnt = (t - base < 64) ? (t - base) : 64;

        if (base > 0) {
            // previous chunk done. Reduce its outputs (before p_lds reuse),
            // commit prefetched x, prefetch next. Same-wave ordering only.
            {
                const v2f* pr = (const v2f*)(p_lds + j * 66);
                v2f s2 = (v2f){0.f, 0.f};
                #pragma unroll
                for (int i = 0; i < 32; ++i) s2 += pr[i];
                outb[base - 64 + j] = frcp(1.f + __expf(-(s2.x + s2.y + bdv)));
            }
            {
                h8 o0, o1, o2;
                #pragma unroll
                for (int i = 0; i < 4; ++i) {
                    o0[i]     = (_Float16)pf[0][i];  o0[4 + i] = (_Float16)pf[1][i];
                    o1[i]     = (_Float16)pf[2][i];  o1[4 + i] = (_Float16)pf[3][i];
                    o2[i]     = (_Float16)pf[4][i];  o2[4 + i] = (_Float16)pf[5][i];
                }
                h8* dst = (h8*)(xbuf + j * 24);
                dst[0] = o0; dst[1] = o1; dst[2] = o2;
            }
            if (base + 64 < t) {
                const v4f* ns = (const v4f*)(xb + (size_t)(base + 64) * 24 + j * 24);
                #pragma unroll
                for (int i = 0; i < 6; ++i) pf[i] = ns[i];
            }
        }

        for (int c = 0; c < cnt; ++c) {
            // ---- issue ALL LDS reads up front: h first, then x row c ----
            const h8* hp = (const h8*)h16;
            h8 hv[8];
            #pragma unroll
            for (int i = 0; i < 8; ++i) hv[i] = hp[i];
            const h8* xp = (const h8*)(xbuf + c * 24);
            h8 xa = xp[0], xcv = xp[1], xe = xp[2];

            // ---- x-part (W-dots) FIRST: independent of hv, issues while
            //      the h-read is still in flight ----
            float ran = brn;
            DOT4(ran, Wr, 0, xa); DOT4(ran, Wr, 4, xcv); DOT4(ran, Wr, 8, xe);
            float zan = bzn;
            DOT4(zan, Wz, 0, xa); DOT4(zan, Wz, 4, xcv); DOT4(zan, Wz, 8, xe);
            float xca = b0c2;
            DOT4(xca, Wc, 0, xa); DOT4(xca, Wc, 4, xcv); DOT4(xca, Wc, 8, xe);

            // ---- h-part (U-dots): r first so its exp cooks under z/c ----
            #pragma unroll
            for (int i = 0; i < 8; ++i) { DOT4(ran, Ur, 4 * i, hv[i]); }
            const float er = __expf(ran);        // latency hidden under z/c dots

            #pragma unroll
            for (int i = 0; i < 8; ++i) { DOT4(zan, Uz, 4 * i, hv[i]); }
            const float ez = __expf(zan);        // cooks under c dots

            float ca = b1c2;                     // 2*(hc+b1c)
            #pragma unroll
            for (int i = 0; i < 8; ++i) { DOT4(ca, Uc, 4 * i, hv[i]); }

            const float r  = frcp(1.f + er);
            const float z  = frcp(1.f + ez);
            const float y  = fmaf(r, ca, xca);                 // 2*(xc + r*hc)
            const float cg = 1.f - 2.f * frcp(1.f + __expf(y));
            const float hn = fmaf(z, hold - cg, cg);           // z*h + (1-z)*c
            hold = hn;

            h16[j] = (_Float16)hn;          // next step's state (ds_write_b16)
            p_lds[c * 66 + j] = hn * wdj;   // output partial
        }
    }

    // ---- final (possibly partial) chunk reduce ----
    const int lastbase = ((t - 1) >> 6) << 6;
    const int lastcnt  = t - lastbase;
    if (j < lastcnt) {
        const v2f* pr = (const v2f*)(p_lds + j * 66);
        v2f s2 = (v2f){0.f, 0.f};
        #pragma unroll
        for (int i = 0; i < 32; ++i) s2 += pr[i];
        const float o = frcp(1.f + __expf(-(s2.x + s2.y + bdv)));
        outb[lastbase + j] = o;
        if (j == lastcnt - 1) o_last = o;
    }
    // ---- constant tail fill (same-wave visibility; R3-proven pattern) ----
    const float fill = o_last;
    for (int i = t + j; i < 1024; i += 64) outb[i] = fill;
}

extern "C" void kernel_launch(void* const* d_in, const int* in_sizes, int n_in,
                              void* d_out, int out_size, void* d_ws, size_t ws_size,
                              hipStream_t stream) {
    (void)in_sizes; (void)n_in; (void)d_ws; (void)ws_size; (void)out_size;
    const float* x  = (const float*)d_in[0];
    const int*   t  = (const int*)d_in[1];
    const float* W  = (const float*)d_in[2];
    const float* U  = (const float*)d_in[3];
    const float* bb = (const float*)d_in[4];
    const float* Wd = (const float*)d_in[5];
    const float* bd = (const float*)d_in[6];
    float* out = (float*)d_out;

    hipLaunchKernelGGL(gru1_kernel, dim3(512), dim3(64), 0, stream,
                       x, t, W, U, bb, Wd, bd, out);
}